// Round 1
// 145.392 us; speedup vs baseline: 1.0063x; 1.0063x over previous
//
#include <hip/hip_runtime.h>
#include <math.h>

#define NG 8
#define NLINES 200000
#define NFACES 200000
#define NFACE_BLOCKS 782          // ceil(200000/256)
#define NLINE_BLOCKS 6250         // 200000*8/256 exactly
#define PF_BASE  28800000         // float offset of faces pf region
#define BAR_BASE 32400000         // float offset of faces bar region

// fast 1-ulp hardware ops
__device__ __forceinline__ float frcp(float x)  { return __builtin_amdgcn_rcpf(x); }
__device__ __forceinline__ float frsq(float x)  { return __builtin_amdgcn_rsqf(x); }
__device__ __forceinline__ float fsqrt(float x) { return __builtin_amdgcn_sqrtf(x); }

// cos/sin of 2*pi/8*g evaluated in f32 (matches jnp.cos/sin of f32 angles)
__constant__ float2 c_cs[8] = {
  {  1.0f,            0.0f           },
  {  0.70710678f,     0.70710678f    },
  { -4.37113883e-08f, 1.0f           },
  { -0.70710678f,     0.70710678f    },
  { -1.0f,           -8.74227766e-08f},
  { -0.70710678f,    -0.70710678f    },
  {  1.19248806e-08f,-1.0f           },
  {  0.70710678f,    -0.70710678f    },
};
__constant__ float c_fr[4] = {0.2f, 0.4f, 0.6f, 0.8f};

struct F3 { float x, y, z; };
__device__ __forceinline__ F3 sub3(F3 a, F3 b) { return {a.x - b.x, a.y - b.y, a.z - b.z}; }
__device__ __forceinline__ float dot3(F3 a, F3 b) { return a.x * b.x + a.y * b.y + a.z * b.z; }

__device__ __forceinline__ void cone_intersect(F3 va, float ra, F3 vb, F3 vc, F3 n,
                                               F3& ip, F3& sn)
{
  const float COS_PHI = 6.123234e-17f;
  const float c = -4.37113883e-08f;   // cos(float32(pi/2))
  const float s = 1.0f;               // sin(float32(pi/2))
  const float t = 1.0f - c;           // rounds to 1.0f

  F3 cab = sub3(vb, va);
  F3 cac = sub3(vc, va);
  float invab = frsq(dot3(cab, cab));
  float invac = frsq(dot3(cac, cac));
  float cr = COS_PHI * ra;
  F3 pab = {va.x + cab.x * invab * cr, va.y + cab.y * invab * cr, va.z + cab.z * invab * cr};
  F3 pac = {va.x + cac.x * invac * cr, va.y + cac.y * invac * cr, va.z + cac.z * invac * cr};

  float u = cab.x, v = cab.y, w = cab.z;
  float d0 = (u * u + (v * v + w * w) * c) * n.x + (u * v * t - w * s) * n.y + (u * w * t + v * s) * n.z;
  float d1 = (u * v * t + w * s) * n.x + (v * v + (u * u + w * w) * c) * n.y + (v * w * t - u * s) * n.z;
  float d2 = (u * w * t - v * s) * n.x + (v * w * t + u * s) * n.y + (w * w + (u * u + v * v) * c) * n.z;
  F3 dir = {d0, d1, d2};

  F3 dpp = sub3(pac, pab);
  float tt = dot3(dpp, cac) * frcp(dot3(dir, cac));
  ip = {pab.x + dir.x * tt, pab.y + dir.y * tt, pab.z + dir.z * tt};
  F3 vap = sub3(ip, va);
  float snm = fsqrt(ra * ra - dot3(vap, vap));
  sn = {snm * n.x, snm * n.y, snm * n.z};
}

// (256, 8): force <=64 VGPR so 8 blocks/CU are resident (LDS limit: 8 x 18432B).
// Faces path restructured cone-at-a-time below to make 64 VGPR feasible.
__global__ __launch_bounds__(256, 8) void fused_kernel(
    const float4* __restrict__ skel, const int2* __restrict__ lines,
    const int* __restrict__ faces, float* __restrict__ out)
{
  __shared__ float lds[256 * 18];   // 18432 B -> 8 blocks/CU
  const int tid = threadIdx.x;

  if (blockIdx.x >= NFACE_BLOCKS) {
    // ---------------- lines path (numerics identical to baseline) ----------------
    const int lb = blockIdx.x - NFACE_BLOCKS;
    const int p  = lb * 256 + tid;     // pair index in [0, 1.6e6)
    const int li = p >> 3;
    const int g  = p & 7;

    int2 ln = lines[li];
    float4 s1 = skel[ln.x];
    float4 s2 = skel[ln.y];
    float r1 = s1.w, r2 = s2.w;

    float cx = s2.x - s1.x, cy = s2.y - s1.y, cz = s2.z - s1.z;
    float pz = (-cx - cy) * frcp(cz);
    float invp = frsq(2.0f + pz * pz);
    float d0x = invp, d0y = invp, d0z = pz * invp;
    float invc = frsq(cx * cx + cy * cy + cz * cz);
    float ax = cx * invc, ay = cy * invc, az = cz * invc;
    float kx = ay * d0z - az * d0y;
    float ky = az * d0x - ax * d0z;
    float kz = ax * d0y - ay * d0x;
    float dd = ax * d0x + ay * d0y + az * d0z;

    float2 cs = c_cs[g];
    float cA = cs.x, sA = cs.y, omc = 1.0f - cA;
    float rx = d0x * cA + kx * sA + (ax * dd) * omc;
    float ry = d0y * cA + ky * sA + (ay * dd) * omc;
    float rz = d0z * cA + kz * sA + (az * dd) * omc;
    float invr = frsq(rx * rx + ry * ry + rz * rz);
    float nx = rx * invr, ny = ry * invr, nz = rz * invr;

    float p1x = s1.x + nx * r1, p1y = s1.y + ny * r1, p1z = s1.z + nz * r1;
    float p2x = s2.x + nx * r2, p2y = s2.y + ny * r2, p2z = s2.z + nz * r2;

    float* L = &lds[tid * 18];
    L[0] = p1x; L[1] = p1y; L[2] = p1z;
    L[3] = p2x; L[4] = p2y; L[5] = p2z;
    float dx = p2x - p1x, dy = p2y - p1y, dz = p2z - p1z;
#pragma unroll
    for (int d = 0; d < 4; ++d) {
      float fr = c_fr[d];
      L[6 + 3 * d + 0] = p1x + dx * fr;
      L[6 + 3 * d + 1] = p1y + dy * fr;
      L[6 + 3 * d + 2] = p1z + dz * fr;
    }
    __syncthreads();

    const float4* lv = (const float4*)lds;
    float4* ov = (float4*)(out + (size_t)lb * (256 * 18));
#pragma unroll
    for (int v = tid; v < 1152; v += 256) ov[v] = lv[v];
  } else {
    // ---------------- faces path (cone-at-a-time, low live set) ----------------
    const int blk0 = blockIdx.x * 256;
    const int f = blk0 + tid;
    const int cnt = (NFACES - blk0) < 256 ? (NFACES - blk0) : 256;

    float b0 = 0, b1 = 0, b2 = 0, b3 = 0, b4 = 0, b5 = 0;
    if (f < NFACES) {
      int i0 = faces[3 * f + 0], i1 = faces[3 * f + 1], i2 = faces[3 * f + 2];
      float4 s1 = skel[i0], s2 = skel[i1], s3 = skel[i2];
      F3 v1 = {s1.x, s1.y, s1.z}; float r1 = s1.w;
      F3 v2 = {s2.x, s2.y, s2.z}; float r2 = s2.w;
      F3 v3 = {s3.x, s3.y, s3.z}; float r3 = s3.w;

      F3 e1 = sub3(v1, v2);
      F3 e2 = sub3(v1, v3);
      F3 crx = {e1.y * e2.z - e1.z * e2.y, e1.z * e2.x - e1.x * e2.z, e1.x * e2.y - e1.y * e2.x};
      float invn = frsq(dot3(crx, crx));
      F3 nrm = {crx.x * invn, crx.y * invn, crx.z * invn};

      float* P = &lds[tid * 18];

      // cone 1: write pf[0] (ip1+sn1) and pf[3] (ip1-sn1), start barycenter sums
      {
        F3 ip, sn;
        cone_intersect(v1, r1, v2, v3, nrm, ip, sn);
        float qx = ip.x + sn.x, qy = ip.y + sn.y, qz = ip.z + sn.z;
        float wx = ip.x - sn.x, wy = ip.y - sn.y, wz = ip.z - sn.z;
        P[0] = qx; P[1] = qy; P[2] = qz;
        P[9] = wx; P[10] = wy; P[11] = wz;
        b0 = qx; b1 = qy; b2 = qz; b3 = wx; b4 = wy; b5 = wz;
      }
      // cone 2: pf[1], pf[4]
      {
        F3 ip, sn;
        cone_intersect(v2, r2, v1, v3, nrm, ip, sn);
        float qx = ip.x + sn.x, qy = ip.y + sn.y, qz = ip.z + sn.z;
        float wx = ip.x - sn.x, wy = ip.y - sn.y, wz = ip.z - sn.z;
        P[3] = qx; P[4] = qy; P[5] = qz;
        P[12] = wx; P[13] = wy; P[14] = wz;
        b0 += qx; b1 += qy; b2 += qz; b3 += wx; b4 += wy; b5 += wz;
      }
      // cone 3: pf[2], pf[5]
      {
        F3 ip, sn;
        cone_intersect(v3, r3, v1, v2, nrm, ip, sn);
        float qx = ip.x + sn.x, qy = ip.y + sn.y, qz = ip.z + sn.z;
        float wx = ip.x - sn.x, wy = ip.y - sn.y, wz = ip.z - sn.z;
        P[6] = qx; P[7] = qy; P[8] = qz;
        P[15] = wx; P[16] = wy; P[17] = wz;
        b0 += qx; b1 += qy; b2 += qz; b3 += wx; b4 += wy; b5 += wz;
      }
      // same left-assoc order as ((q_c1 + q_c2) + q_c3) * third
      const float third = 0.33333334f;
      b0 *= third; b1 *= third; b2 *= third;
      b3 *= third; b4 *= third; b5 *= third;
    }
    __syncthreads();

    // pf copy-out (cnt*18 always divisible by 4 here: cnt is 256 or 64)
    {
      int nfl = cnt * 18;
      float* opf = out + PF_BASE + (size_t)blk0 * 18;
      const float4* lp = (const float4*)lds;
      float4* op4 = (float4*)opf;
      int nv = nfl >> 2;
      for (int v = tid; v < nv; v += 256) op4[v] = lp[v];
      for (int v = (nv << 2) + tid; v < nfl; v += 256) opf[v] = lds[v];
    }
    __syncthreads();   // all pf reads done before reuse

    if (f < NFACES) {
      float* B = &lds[tid * 6];
      B[0] = b0; B[1] = b1; B[2] = b2; B[3] = b3; B[4] = b4; B[5] = b5;
    }
    __syncthreads();

    // bar copy-out
    {
      int nfl = cnt * 6;
      float* ob = out + BAR_BASE + (size_t)blk0 * 6;
      const float4* lb4 = (const float4*)lds;
      float4* ob4 = (float4*)ob;
      int nv = nfl >> 2;
      for (int v = tid; v < nv; v += 256) ob4[v] = lb4[v];
      for (int v = (nv << 2) + tid; v < nfl; v += 256) ob[v] = lds[v];
    }
  }
}

extern "C" void kernel_launch(void* const* d_in, const int* in_sizes, int n_in,
                              void* d_out, int out_size, void* d_ws, size_t ws_size,
                              hipStream_t stream)
{
  const float4* skel  = (const float4*)d_in[0];
  const int2*   lines = (const int2*)d_in[1];
  const int*    faces = (const int*)d_in[2];
  float* out = (float*)d_out;

  fused_kernel<<<NFACE_BLOCKS + NLINE_BLOCKS, 256, 0, stream>>>(skel, lines, faces, out);
}